// Round 5
// baseline (322.977 us; speedup 1.0000x reference)
//
#include <hip/hip_runtime.h>

// SIZE=65536 nodes, MAX_EDGES=16777216.
// out[i] = bias[i] + sum over edges e with dst[e]==i of x[src[e]]*w[e].
//
// R1: global fp32 atomics ~20.6 G/s -> LDS histograms.
// R2: batched guarded gathers / ds_adds.
// R3: ~135us constant harness overhead; hist is the only real cost.
// R4: pipeline + UNconditional gathers regressed (141->190): doubling
//     gathers 16M->32M costs ~50us => gather term is L2-transaction BW
//     (16M x 64B lines ~ 1GB L2 ~ 29us floor) + latency exposure.
//     KEPT: XCD-pairing swizzle (FETCH 198->101MB: chunk-siblings share L2).
// R5: RANGES=4 (2 blocks/CU): occupancy 42->80% worked but 2x stream scan
//     ate the gain (141->156). S~17us/scan, G~49us, O~50us @16w.
// R6/R7: unroll x2 batching: 141->133us but VGPR=32 proves the compiler
//     re-serialized the batch — divergent `if` guards around each gather
//     are control-flow fences that block load clustering.
// R8: BRANCHLESS inner loop. x[s] is always a valid address; the guard only
//     avoids duplicate work. addr = guard ? s : 0 (masked lanes hit the
//     x[0] broadcast line, L1-resident, no extra L2 traffic);
//     v = guard ? xv*w : 0; ds_add(h[bin & (BINS-1)], v) unconditionally
//     (masked lanes add 0.0 to a scattered real bin -- harmless). Zero
//     branches -> 16 independent gathers cluster under one vmcnt.

#define NNODES  65536
#define NEDGES  16777216
#define RANGES  2
#define BINS    (NNODES / RANGES)   // 32768 bins -> 128 KB dynamic LDS
#define THREADS 1024
#define NCOPIES 128                 // private output copies in ws (32 MB)
#define GROUPS  16
#define CPG     (NCOPIES / GROUPS)  // 8 copies per reduce group

// ---------------- Stage 1: LDS histograms ----------------
// Swizzle (B==128, grid=256): r = bit3, c = b[0:3) | b[4:8)<<3.
// The 2 blocks sharing chunk c differ only in bit 3 -> same b%8 -> same XCD
// under round-robin placement -> the duplicate chunk read is an L2 hit.
__global__ __launch_bounds__(THREADS, 4) void hist_kernel(
    const float* __restrict__ x,
    const float* __restrict__ w,
    const int*   __restrict__ src,
    const int*   __restrict__ dst,
    float*       __restrict__ ws,
    int B)
{
    extern __shared__ float h[];   // BINS floats = 128 KB

    const int b = blockIdx.x;
    int r, c;
    if (B == NCOPIES) {
        r = (b >> 3) & (RANGES - 1);
        c = (b & 7) | ((b >> 4) << 3);
    } else {
        r = b & (RANGES - 1);
        c = b >> 1;
    }
    const int lo = r * BINS;

    for (int i = threadIdx.x; i < BINS; i += THREADS) h[i] = 0.0f;
    __syncthreads();

    const int4*   src4 = (const int4*)src;
    const int4*   dst4 = (const int4*)dst;
    const float4* wgt4 = (const float4*)w;

    const int n8     = NEDGES / 8;
    const int stride = B * THREADS;
    int g = c * THREADS + (int)threadIdx.x;       // < stride always

    if ((n8 % (2 * stride)) == 0 && n8 >= 2 * stride) {
        // ------ fast path: 2 groups (16 edges) per iteration, branchless ------
        const int niter2 = n8 / (2 * stride);     // 8 when B=128
        for (int it = 0; it < niter2; ++it, g += 2 * stride) {
            const int ga = g;
            const int gb = g + stride;

            // All stream loads for both groups issued back-to-back.
            int4   sA0 = src4[2 * ga], sA1 = src4[2 * ga + 1];
            int4   sB0 = src4[2 * gb], sB1 = src4[2 * gb + 1];
            int4   dA0 = dst4[2 * ga], dA1 = dst4[2 * ga + 1];
            int4   dB0 = dst4[2 * gb], dB1 = dst4[2 * gb + 1];
            float4 wA0 = wgt4[2 * ga], wA1 = wgt4[2 * ga + 1];
            float4 wB0 = wgt4[2 * gb], wB1 = wgt4[2 * gb + 1];

            int s[16] = { sA0.x, sA0.y, sA0.z, sA0.w,
                          sA1.x, sA1.y, sA1.z, sA1.w,
                          sB0.x, sB0.y, sB0.z, sB0.w,
                          sB1.x, sB1.y, sB1.z, sB1.w };
            unsigned bin[16] = {
                (unsigned)(dA0.x - lo), (unsigned)(dA0.y - lo),
                (unsigned)(dA0.z - lo), (unsigned)(dA0.w - lo),
                (unsigned)(dA1.x - lo), (unsigned)(dA1.y - lo),
                (unsigned)(dA1.z - lo), (unsigned)(dA1.w - lo),
                (unsigned)(dB0.x - lo), (unsigned)(dB0.y - lo),
                (unsigned)(dB0.z - lo), (unsigned)(dB0.w - lo),
                (unsigned)(dB1.x - lo), (unsigned)(dB1.y - lo),
                (unsigned)(dB1.z - lo), (unsigned)(dB1.w - lo) };
            float wv[16] = { wA0.x, wA0.y, wA0.z, wA0.w,
                             wA1.x, wA1.y, wA1.z, wA1.w,
                             wB0.x, wB0.y, wB0.z, wB0.w,
                             wB1.x, wB1.y, wB1.z, wB1.w };

            // Branchless gather addresses: masked lanes read x[0] (one
            // broadcast line, L1-resident -> no extra L2 transactions).
            int addr[16];
            #pragma unroll
            for (int k = 0; k < 16; ++k)
                addr[k] = (bin[k] < (unsigned)BINS) ? s[k] : 0;

            // 16 independent unconditional gathers -> cluster under one wait.
            float xv[16];
            #pragma unroll
            for (int k = 0; k < 16; ++k) xv[k] = x[addr[k]];

            // Branchless combine + unconditional ds_add: masked lanes add
            // 0.0f to a scattered real bin (value unchanged, no hotspot).
            #pragma unroll
            for (int k = 0; k < 16; ++k) {
                float v = (bin[k] < (unsigned)BINS) ? xv[k] * wv[k] : 0.0f;
                atomicAdd(&h[bin[k] & (BINS - 1)], v);
            }
        }
    } else {
        // -------- generic guarded loop --------
        for (; g < n8; g += stride) {
            int4   sa = src4[2 * g], sb = src4[2 * g + 1];
            int4   da = dst4[2 * g], db = dst4[2 * g + 1];
            float4 wa = wgt4[2 * g], wb = wgt4[2 * g + 1];

            int      s[8]  = { sa.x, sa.y, sa.z, sa.w, sb.x, sb.y, sb.z, sb.w };
            unsigned bin[8] = {
                (unsigned)(da.x - lo), (unsigned)(da.y - lo),
                (unsigned)(da.z - lo), (unsigned)(da.w - lo),
                (unsigned)(db.x - lo), (unsigned)(db.y - lo),
                (unsigned)(db.z - lo), (unsigned)(db.w - lo) };
            float    wv[8] = { wa.x, wa.y, wa.z, wa.w, wb.x, wb.y, wb.z, wb.w };

            float v[8];
            #pragma unroll
            for (int k = 0; k < 8; ++k) {
                v[k] = 0.0f;
                if (bin[k] < (unsigned)BINS) v[k] = x[s[k]] * wv[k];
            }
            #pragma unroll
            for (int k = 0; k < 8; ++k) {
                if (bin[k] < (unsigned)BINS) atomicAdd(&h[bin[k]], v[k]);
            }
        }
    }
    __syncthreads();

    float* outc = ws + (size_t)c * NNODES + lo;
    for (int i = threadIdx.x; i < BINS; i += THREADS) outc[i] = h[i];
}

// ---------------- Stage 2a: tree reduce 128 -> 16 (in-place) ----------------
__global__ __launch_bounds__(256) void reduceA_kernel(float* __restrict__ ws)
{
    const int NB = NNODES / (256 * 4);          // 64 slice-blocks per group
    int g  = blockIdx.x / NB;
    int jb = blockIdx.x % NB;
    int i4 = jb * 256 + (int)threadIdx.x;       // float4 index in [0, 16384)

    float4* w4 = (float4*)ws;
    const int stride4 = NNODES / 4;

    float4 acc = w4[(size_t)(g * CPG) * stride4 + i4];
    #pragma unroll
    for (int cc = 1; cc < CPG; ++cc) {
        float4 t = w4[(size_t)(g * CPG + cc) * stride4 + i4];
        acc.x += t.x; acc.y += t.y; acc.z += t.z; acc.w += t.w;
    }
    w4[(size_t)(g * CPG) * stride4 + i4] = acc;
}

// ---------------- Stage 2b: 16 partials + bias -> out ----------------
__global__ __launch_bounds__(256) void reduceB_kernel(
    const float* __restrict__ ws,
    const float* __restrict__ bias,
    float*       __restrict__ out)
{
    int i4 = blockIdx.x * 256 + (int)threadIdx.x;  // float4 index
    const float4* w4 = (const float4*)ws;
    const int stride4 = NNODES / 4;

    float4 acc = ((const float4*)bias)[i4];
    #pragma unroll
    for (int g = 0; g < GROUPS; ++g) {
        float4 t = w4[(size_t)(g * CPG) * stride4 + i4];
        acc.x += t.x; acc.y += t.y; acc.z += t.z; acc.w += t.w;
    }
    ((float4*)out)[i4] = acc;
}

// ---------------- Generic fallback reduce (B != NCOPIES) ----------------
__global__ __launch_bounds__(256) void reduce_generic_kernel(
    const float* __restrict__ ws,
    const float* __restrict__ bias,
    float*       __restrict__ out,
    int B)
{
    int i = blockIdx.x * 256 + (int)threadIdx.x;
    float acc = bias[i];
    for (int cc = 0; cc < B; ++cc) acc += ws[(size_t)cc * NNODES + i];
    out[i] = acc;
}

// ---------------- Fallback: global atomics (tiny ws) ----------------
__global__ __launch_bounds__(256) void init_out_kernel(
    const float* __restrict__ bias, float* __restrict__ out)
{
    int i = blockIdx.x * blockDim.x + threadIdx.x;
    if (i < NNODES) out[i] = bias[i];
}

__global__ __launch_bounds__(256) void edge_atomic_kernel(
    const float* __restrict__ x, const float* __restrict__ w,
    const int* __restrict__ src, const int* __restrict__ dst,
    float* __restrict__ out)
{
    const int n4 = NEDGES / 4;
    int tid = blockIdx.x * blockDim.x + threadIdx.x;
    int stride = gridDim.x * blockDim.x;
    for (int i = tid; i < n4; i += stride) {
        int4 s = ((const int4*)src)[i];
        int4 d = ((const int4*)dst)[i];
        float4 ww = ((const float4*)w)[i];
        atomicAdd(&out[d.x], x[s.x] * ww.x);
        atomicAdd(&out[d.y], x[s.y] * ww.y);
        atomicAdd(&out[d.z], x[s.z] * ww.z);
        atomicAdd(&out[d.w], x[s.w] * ww.w);
    }
}

extern "C" void kernel_launch(void* const* d_in, const int* in_sizes, int n_in,
                              void* d_out, int out_size, void* d_ws, size_t ws_size,
                              hipStream_t stream) {
    const float* x    = (const float*)d_in[0];
    const float* w    = (const float*)d_in[1];
    const float* bias = (const float*)d_in[2];
    const int*   src  = (const int*)d_in[3];
    const int*   dst  = (const int*)d_in[4];
    float* out = (float*)d_out;
    float* ws  = (float*)d_ws;

    size_t copies = ws_size / ((size_t)NNODES * sizeof(float));
    int B = (int)(copies < NCOPIES ? copies : NCOPIES);

    if (B >= 1) {
        // 256 blocks (B=128 x 2 ranges), 1 block/CU, 128 KB dynamic LDS.
        hist_kernel<<<B * RANGES, THREADS, BINS * sizeof(float), stream>>>(
            x, w, src, dst, ws, B);
        if (B == NCOPIES) {
            reduceA_kernel<<<GROUPS * (NNODES / 1024), 256, 0, stream>>>(ws);
            reduceB_kernel<<<NNODES / 1024, 256, 0, stream>>>(ws, bias, out);
        } else {
            reduce_generic_kernel<<<NNODES / 256, 256, 0, stream>>>(ws, bias, out, B);
        }
    } else {
        init_out_kernel<<<NNODES / 256, 256, 0, stream>>>(bias, out);
        edge_atomic_kernel<<<4096, 256, 0, stream>>>(x, w, src, dst, out);
    }
}